// Round 1
// 455.496 us; speedup vs baseline: 1.3252x; 1.3252x over previous
//
#include <hip/hip_runtime.h>

// DropBlock on (B,C,H,W)=(64,256,56,56), block_size=7, drop_prob=0.1
// mask_u is (B,C,50,50); gamma = 0.1/49 * 56^2/50^2.

#define BB 64
#define CC 256
#define HH 56
#define WW 56
#define HMM 50
#define WMM 50
#define BS 7

static constexpr unsigned int NPLANE = BB * CC;            // 16384
static constexpr unsigned int NTOT   = BB * CC * HH * WW;  // 51380224
static constexpr unsigned int NV     = NTOT / 4;           // 12845056 float4s

// One wave (64 threads) per (b,c) plane.
// Builds the 7x7-dilated drop mask as 56 uint64 row bitmasks and writes the
// per-plane dropped-pixel count to plane_cnt[plane] (NO global atomic: 16384
// same-address atomicAdds serialized at one L2 line and cost ~200us last round).
__global__ void __launch_bounds__(64) dropblock_mask_kernel(
    const float* __restrict__ mask_u,
    unsigned long long* __restrict__ rowmask,
    unsigned int* __restrict__ plane_cnt,
    float gamma)
{
    const unsigned int plane = blockIdx.x;
    const unsigned int lane  = threadIdx.x;  // 0..63
    const float* mu = mask_u + (size_t)plane * (HMM * WMM);

    __shared__ unsigned long long rsh[HMM];  // horizontally dilated row masks

    // Row-by-row: lanes 0..49 load one element each; ballot -> 50-bit row mask.
    #pragma unroll 5
    for (int i = 0; i < HMM; ++i) {
        float v = (lane < WMM) ? mu[i * WMM + lane] : 1.0f;  // 1.0 >= gamma -> bit 0
        unsigned long long m = __ballot(v < gamma);
        // horizontal dilation: OR of shifts 0..6 (bits spread to cols j..j+6)
        unsigned long long d = m | (m << 1);  // shifts {0,1}
        d |= d << 2;                          // {0..3}
        d |= d << 3;                          // {0..6}
        if (lane == 0) rsh[i] = d;
    }
    __syncthreads();

    // Vertical dilation: output row i = OR of dilated rows (i-6..i) ∩ [0,50)
    unsigned long long blocked = 0ull;
    if (lane < HH) {
        int lo = (int)lane - (BS - 1); if (lo < 0) lo = 0;
        int hi = (int)lane;            if (hi > HMM - 1) hi = HMM - 1;
        for (int di = lo; di <= hi; ++di) blocked |= rsh[di];
        rowmask[plane * HH + lane] = blocked;
    }

    // dropped-pixel count for this plane -> plain per-plane store (no atomic)
    unsigned int cnt = __popcll(blocked);  // lanes >= 56 have blocked==0
    #pragma unroll
    for (int off = 32; off > 0; off >>= 1)
        cnt += __shfl_down(cnt, off, 64);
    if (lane == 0) plane_cnt[plane] = cnt;
}

// Single-block reduction of the 16384 per-plane counts -> scale factor.
// 1024 threads x 4 uint4 loads each; data is L2-resident (64 KB).
__global__ void __launch_bounds__(1024) dropblock_scale_kernel(
    const unsigned int* __restrict__ plane_cnt,
    float* __restrict__ scale_out)
{
    __shared__ unsigned int ssum[16];
    const unsigned int t = threadIdx.x;

    const uint4* pc4 = reinterpret_cast<const uint4*>(plane_cnt);  // 4096 uint4
    uint4 a = pc4[t];
    uint4 b = pc4[t + 1024];
    uint4 c = pc4[t + 2048];
    uint4 d = pc4[t + 3072];
    unsigned int s = a.x + a.y + a.z + a.w
                   + b.x + b.y + b.z + b.w
                   + c.x + c.y + c.z + c.w
                   + d.x + d.y + d.z + d.w;

    #pragma unroll
    for (int off = 32; off > 0; off >>= 1)
        s += __shfl_down(s, off, 64);
    if ((t & 63u) == 0u) ssum[t >> 6] = s;
    __syncthreads();

    if (t < 16) {
        unsigned int v = ssum[t];
        #pragma unroll
        for (int off = 8; off > 0; off >>= 1)
            v += __shfl_down(v, off, 64);
        if (t == 0) {
            // NTOT is exactly representable in fp32; kept-count rounding error
            // <= 2 ulp -> scale rel err ~1e-7, way under threshold.
            *scale_out = (float)NTOT / (float)(NTOT - v);
        }
    }
}

// float4 over the whole tensor: out = x * (dropped ? 0 : scale)
__global__ void __launch_bounds__(256) dropblock_apply_kernel(
    const float* __restrict__ x,
    const unsigned long long* __restrict__ rowmask,
    const float* __restrict__ scale_ptr,
    float* __restrict__ out)
{
    unsigned int idx = blockIdx.x * 256u + threadIdx.x;
    if (idx >= NV) return;

    const float scale = *scale_ptr;  // uniform scalar load, precomputed

    // idx -> (plane, row, col) ; 784 float4s per plane, 14 per row
    unsigned int plane = idx / (HH * WW / 4);            // / 784
    unsigned int rem   = idx - plane * (HH * WW / 4);
    unsigned int row   = rem / (WW / 4);                 // / 14
    unsigned int colv  = rem - row * (WW / 4);
    unsigned int col   = colv * 4;

    unsigned long long rm = rowmask[plane * HH + row];
    float4 xv = reinterpret_cast<const float4*>(x)[idx];
    float4 o;
    o.x = ((rm >> (col + 0)) & 1ull) ? 0.0f : xv.x * scale;
    o.y = ((rm >> (col + 1)) & 1ull) ? 0.0f : xv.y * scale;
    o.z = ((rm >> (col + 2)) & 1ull) ? 0.0f : xv.z * scale;
    o.w = ((rm >> (col + 3)) & 1ull) ? 0.0f : xv.w * scale;
    reinterpret_cast<float4*>(out)[idx] = o;
}

extern "C" void kernel_launch(void* const* d_in, const int* in_sizes, int n_in,
                              void* d_out, int out_size, void* d_ws, size_t ws_size,
                              hipStream_t stream) {
    const float* x      = (const float*)d_in[0];
    const float* mask_u = (const float*)d_in[1];
    float* out          = (float*)d_out;

    // ws layout (everything fully overwritten each call -> re-poison safe,
    // no memset needed):
    //   [0, 64)           : scale (float, in its own cache line)
    //   [64, 64+65536)    : per-plane drop counts (16384 u32)
    //   [65600, +7340032) : 16384 planes * 56 rows * uint64 row bitmasks
    float* scale_ws             = (float*)d_ws;
    unsigned int* plane_cnt     = (unsigned int*)((char*)d_ws + 64);
    unsigned long long* rowmask = (unsigned long long*)((char*)d_ws + 65600);

    // gamma computed in double then cast to fp32, matching JAX's weak-typed
    // promotion of the Python float in (mask_u < gamma).
    const double gd = 0.1 / ((double)BS * BS) * ((double)HH * HH) /
                      (((double)HH - BS + 1.0) * ((double)HH - BS + 1.0));
    const float gamma = (float)gd;

    dropblock_mask_kernel<<<NPLANE, 64, 0, stream>>>(mask_u, rowmask, plane_cnt, gamma);

    dropblock_scale_kernel<<<1, 1024, 0, stream>>>(plane_cnt, scale_ws);

    dropblock_apply_kernel<<<(NV + 255u) / 256u, 256, 0, stream>>>(
        x, rowmask, scale_ws, out);
}